// Round 5
// baseline (271.292 us; speedup 1.0000x reference)
//
#include <hip/hip_runtime.h>

#define B_ 8
#define L_ 2048
#define E_ 256
#define H_ 4
#define D_ 64

typedef __bf16 bf16;
typedef __bf16 bf16x8 __attribute__((ext_vector_type(8)));
typedef __bf16 bf16x4 __attribute__((ext_vector_type(4)));
typedef float  f32x4  __attribute__((ext_vector_type(4)));
typedef float  f32x8  __attribute__((ext_vector_type(8)));
typedef float  f32x16 __attribute__((ext_vector_type(16)));

// Shat = (q.k)/8 * log2(e); softmax entirely in exp2 domain.
#define QSCALE 0.1803368801111244f

__device__ __forceinline__ float fexp2(float x) { return __builtin_amdgcn_exp2f(x); }
__device__ __forceinline__ float flog2(float x) { return __builtin_amdgcn_logf(x); }

// ---------------------------------------------------------------------------
// Kernel 1: repack weights to bf16.
// Wcat[768][256]: rows 0..511 = in_proj_w rows (q,k); rows 512..767 = W_gnn^T
// ---------------------------------------------------------------------------
__global__ void prep_weights(const float* __restrict__ in_proj_w,
                             const float* __restrict__ W_gnn,
                             bf16* __restrict__ Wcat) {
    int r = blockIdx.x;
    int e = threadIdx.x;
    float v = (r < 512) ? in_proj_w[r * E_ + e] : W_gnn[e * E_ + (r - 512)];
    Wcat[r * E_ + e] = (bf16)v;
}

// ---------------------------------------------------------------------------
// Kernel 2: projections (R2-proven config: grid (256,3), 3 blocks/CU).
//   by==0 -> Qs[B,L,E]  (bias + QSCALE folded; col n = h*64+d)
//   by==1 -> Ks[B,L,E]  (bias folded)
//   by==2 -> XWT[B,E,L] = (x @ W_gnn + B_gnn)^T per batch, bf16
// ---------------------------------------------------------------------------
__global__ __launch_bounds__(256, 2) void proj_kernel(
    const float* __restrict__ x, const bf16* __restrict__ Wcat,
    const float* __restrict__ in_proj_b, const float* __restrict__ B_gnn,
    bf16* __restrict__ Qs, bf16* __restrict__ Ks, bf16* __restrict__ XWT) {
    int tid  = threadIdx.x;
    int lane = tid & 63, wave = tid >> 6;
    int l16  = lane & 15, quad = lane >> 4;
    int m0 = blockIdx.x * 64 + wave * 16;
    int by = blockIdx.y;
    int n0 = by * 256;

    f32x4 acc[16];
#pragma unroll
    for (int i = 0; i < 16; i++) acc[i] = (f32x4){0.f, 0.f, 0.f, 0.f};

    const float* xrow = x + (size_t)(m0 + l16) * E_;
    for (int ks = 0; ks < 8; ks++) {
        int koff = ks * 32 + quad * 8;
        f32x8 av = *(const f32x8*)&xrow[koff];
        bf16x8 af;
#pragma unroll
        for (int j = 0; j < 8; j++) af[j] = (bf16)av[j];
#pragma unroll
        for (int nt = 0; nt < 16; nt++) {
            bf16x8 bfv = *(const bf16x8*)&Wcat[(size_t)(n0 + nt * 16 + l16) * E_ + koff];
            acc[nt] = __builtin_amdgcn_mfma_f32_16x16x32_bf16(af, bfv, acc[nt], 0, 0, 0);
        }
    }

#pragma unroll
    for (int nt = 0; nt < 16; nt++) {
        int n = n0 + nt * 16 + l16;
        if (by == 0) {
            float bias = in_proj_b[n];
#pragma unroll
            for (int r = 0; r < 4; r++) {
                int m = m0 + quad * 4 + r;
                Qs[(size_t)m * E_ + n] = (bf16)((acc[nt][r] + bias) * QSCALE);
            }
        } else if (by == 1) {
            float bias = in_proj_b[n];
            int col = n - 256;
#pragma unroll
            for (int r = 0; r < 4; r++) {
                int m = m0 + quad * 4 + r;
                Ks[(size_t)m * E_ + col] = (bf16)(acc[nt][r] + bias);
            }
        } else {
            int nc = n - 512;
            float bias = B_gnn[nc];
            int m = m0 + quad * 4;
            int b = m >> 11, l = m & 2047;
            bf16x4 pk;
#pragma unroll
            for (int r = 0; r < 4; r++) pk[r] = (bf16)(acc[nt][r] + bias);
            *(bf16x4*)&XWT[((size_t)b * E_ + nc) * L_ + l] = pk;
        }
    }
}

// ---------------------------------------------------------------------------
// Kernel 3: softmax stats. o[b,h,q] = -log2(4 * sum_k exp2(Shat)).
// R2-proven config: grid (16,4,8)=512 blocks, 32q/wave, high occupancy.
// 32x32x16 C/D: col=lane&31, row=(reg&3)+8*(reg>>2)+4*(lane>>5).
// ---------------------------------------------------------------------------
__global__ __launch_bounds__(256, 4) void stats_kernel(
    const bf16* __restrict__ Qs, const bf16* __restrict__ Ks,
    float* __restrict__ o) {
    __shared__ bf16 ldsK[64 * 72];
    int tid  = threadIdx.x;
    int lane = tid & 63, wave = tid >> 6;
    int r32  = lane & 31, half = lane >> 5;
    int qt = blockIdx.x, h = blockIdx.y, b = blockIdx.z;
    int q0 = qt * 128 + wave * 32;

    bf16x8 qa[4];
    const bf16* qrow = Qs + ((size_t)b * L_ + q0 + r32) * E_ + h * D_;
#pragma unroll
    for (int c = 0; c < 4; c++) qa[c] = *(const bf16x8*)&qrow[c * 16 + half * 8];

    float lsum[16];
#pragma unroll
    for (int i = 0; i < 16; i++) lsum[i] = 0.f;

    const bf16* Kb = Ks + (size_t)b * L_ * E_ + h * D_;
    for (int kt = 0; kt < 32; kt++) {
        __syncthreads();
#pragma unroll
        for (int it = 0; it < 2; it++) {
            int idx = it * 256 + tid;
            int key = idx >> 3, dc = (idx & 7) * 8;
            *(bf16x8*)&ldsK[key * 72 + dc] =
                *(const bf16x8*)&Kb[(size_t)(kt * 64 + key) * E_ + dc];
        }
        __syncthreads();
#pragma unroll
        for (int nt = 0; nt < 2; nt++) {
            f32x16 S = {};
#pragma unroll
            for (int c = 0; c < 4; c++) {
                bf16x8 kb = *(const bf16x8*)&ldsK[(nt * 32 + r32) * 72 + c * 16 + half * 8];
                S = __builtin_amdgcn_mfma_f32_32x32x16_bf16(qa[c], kb, S, 0, 0, 0);
            }
#pragma unroll
            for (int i = 0; i < 16; i++) lsum[i] += fexp2(S[i]);
        }
    }
#pragma unroll
    for (int i = 0; i < 16; i++) {
        float v = lsum[i];
        v += __shfl_xor(v, 1); v += __shfl_xor(v, 2); v += __shfl_xor(v, 4);
        v += __shfl_xor(v, 8); v += __shfl_xor(v, 16);
        lsum[i] = v;
    }
    if (r32 == 0) {
        float* op = o + ((size_t)(b * H_ + h)) * L_ + q0;
#pragma unroll
        for (int i = 0; i < 16; i++) {
            int row = (i & 3) + 8 * (i >> 2) + 4 * half;
            op[row] = -(2.0f + flog2(lsum[i]));
        }
    }
}

// ---------------------------------------------------------------------------
// Kernel 4: pass 2 v6. 512-thread blocks (1/CU), 8 waves = 2/SIMD (TLP back)
// with waves = (4 q-subtiles x 2 n-halves): per-wave XW B-side LDS reads
// halved vs a full-n wave; QK duplicated across the n-half pair (QK is 1/3
// of FLOPs); P buffer per q-subtile shared via benign bit-identical
// duplicate writes. acc = 32q x 128n = 64 AGPR -> fits 2 waves/SIMD.
// ---------------------------------------------------------------------------
__global__ __launch_bounds__(512, 2) void pass2_kernel(
    const bf16* __restrict__ Qs, const bf16* __restrict__ Ks,
    const bf16* __restrict__ XWT, const float* __restrict__ o,
    bf16* __restrict__ Opart) {
    __shared__ bf16 ldsK[64 * 264];      // [64 keys][256 E + 8 pad]   33792 B
    __shared__ bf16 ldsXW[256 * 72];     // [256 n][64 k + 8 pad]      36864 B
    __shared__ bf16 ldsP[4][32 * 72];    // per q-subtile [32 q][72]   18432 B
    __shared__ float ldsO[512];          //                             2048 B -> 91136 B

    int tid  = threadIdx.x;
    int lane = tid & 63, wave = tid >> 6;
    int l16  = lane & 15, quad = lane >> 4;
    int qsub = wave & 3, nh = wave >> 2;
    int qt = blockIdx.x, ksp = blockIdx.y, b = blockIdx.z;
    int q0 = qt * 128;
    int qw = q0 + qsub * 32;

    // stage o table (512 f32, one per thread)
    ldsO[tid] = o[((size_t)(b * H_ + (tid >> 7))) * L_ + q0 + (tid & 127)];

    // Q fragments: [subtile][head][frag], resident whole kernel (64 VGPR)
    bf16x8 qf[2][4][2];
    const bf16* qp = Qs + ((size_t)b * L_ + qw + l16) * E_;
#pragma unroll
    for (int s = 0; s < 2; s++)
#pragma unroll
        for (int h = 0; h < H_; h++) {
            qf[s][h][0] = *(const bf16x8*)&qp[(size_t)s * 16 * E_ + h * 64 + quad * 8];
            qf[s][h][1] = *(const bf16x8*)&qp[(size_t)s * 16 * E_ + h * 64 + 32 + quad * 8];
        }

    f32x4 acc[2][8];
#pragma unroll
    for (int s = 0; s < 2; s++)
#pragma unroll
        for (int i = 0; i < 8; i++) acc[s][i] = (f32x4){0.f, 0.f, 0.f, 0.f};

    const bf16* Kb = Ks + (size_t)b * L_ * E_;
    const bf16* Xb = XWT + (size_t)b * E_ * L_;
    int kbase = ksp * 1024;

    for (int kt = 0; kt < 16; kt++) {
        int k0 = kbase + kt * 64;
        __syncthreads();
        // stage K tile: 64 keys x 256 E (4 bf16x8 units/thread)
#pragma unroll
        for (int it = 0; it < 4; it++) {
            int idx = it * 512 + tid;
            int key = idx >> 5, col = (idx & 31) * 8;
            *(bf16x8*)&ldsK[key * 264 + col] =
                *(const bf16x8*)&Kb[(size_t)(k0 + key) * E_ + col];
        }
        // stage XW tile: 256 n x 64 keys
#pragma unroll
        for (int it = 0; it < 4; it++) {
            int idx = it * 512 + tid;
            int n = idx >> 3, kc = (idx & 7) * 8;
            *(bf16x8*)&ldsXW[n * 72 + kc] =
                *(const bf16x8*)&Xb[(size_t)n * L_ + k0 + kc];
        }
        __syncthreads();

        // P = sum_h exp2(Shat_h + o_h)   (identical on both nh waves)
        f32x4 P[2][4];
#pragma unroll
        for (int s = 0; s < 2; s++)
#pragma unroll
            for (int nt = 0; nt < 4; nt++) P[s][nt] = (f32x4){0.f, 0.f, 0.f, 0.f};

#pragma unroll
        for (int h = 0; h < H_; h++) {
            f32x4 S[2][4];
#pragma unroll
            for (int s = 0; s < 2; s++)
#pragma unroll
                for (int nt = 0; nt < 4; nt++) S[s][nt] = (f32x4){0.f, 0.f, 0.f, 0.f};
#pragma unroll
            for (int nt = 0; nt < 4; nt++) {
                bf16x8 k0f = *(const bf16x8*)&ldsK[(nt * 16 + l16) * 264 + h * 64 + quad * 8];
                bf16x8 k1f = *(const bf16x8*)&ldsK[(nt * 16 + l16) * 264 + h * 64 + 32 + quad * 8];
#pragma unroll
                for (int s = 0; s < 2; s++) {
                    S[s][nt] = __builtin_amdgcn_mfma_f32_16x16x32_bf16(qf[s][h][0], k0f, S[s][nt], 0, 0, 0);
                    S[s][nt] = __builtin_amdgcn_mfma_f32_16x16x32_bf16(qf[s][h][1], k1f, S[s][nt], 0, 0, 0);
                }
            }
#pragma unroll
            for (int s = 0; s < 2; s++)
#pragma unroll
                for (int r = 0; r < 4; r++) {
                    float off = ldsO[h * 128 + qsub * 32 + s * 16 + quad * 4 + r];
#pragma unroll
                    for (int nt = 0; nt < 4; nt++)
                        P[s][nt][r] += fexp2(S[s][nt][r] + off);
                }
        }

        // P transpose (C->A layout) into the q-subtile region (benign dup
        // writes from the nh pair: bit-identical values)
#pragma unroll
        for (int s = 0; s < 2; s++)
#pragma unroll
            for (int nt = 0; nt < 4; nt++)
#pragma unroll
                for (int r = 0; r < 4; r++)
                    ldsP[qsub][(s * 16 + quad * 4 + r) * 72 + nt * 16 + l16] = (bf16)P[s][nt][r];

        bf16x8 pf[2][2];
#pragma unroll
        for (int s = 0; s < 2; s++) {
            pf[s][0] = *(const bf16x8*)&ldsP[qsub][(s * 16 + l16) * 72 + quad * 8];
            pf[s][1] = *(const bf16x8*)&ldsP[qsub][(s * 16 + l16) * 72 + 32 + quad * 8];
        }

        // PV (swapped): D[n][q] += XW[n][k] * P[q][k], n-half per wave
#pragma unroll
        for (int nt = 0; nt < 8; nt++) {
            bf16x8 a0 = *(const bf16x8*)&ldsXW[(nh * 128 + nt * 16 + l16) * 72 + quad * 8];
            bf16x8 a1 = *(const bf16x8*)&ldsXW[(nh * 128 + nt * 16 + l16) * 72 + 32 + quad * 8];
#pragma unroll
            for (int s = 0; s < 2; s++) {
                acc[s][nt] = __builtin_amdgcn_mfma_f32_16x16x32_bf16(a0, pf[s][0], acc[s][nt], 0, 0, 0);
                acc[s][nt] = __builtin_amdgcn_mfma_f32_16x16x32_bf16(a1, pf[s][1], acc[s][nt], 0, 0, 0);
            }
        }
    }

    // store: acc[s][nt] = D[n = nh*128+nt*16+quad*4+r][q = qw+s*16+l16]
    bf16* Ob = Opart + ((size_t)(ksp * B_ + b)) * L_ * E_;
#pragma unroll
    for (int s = 0; s < 2; s++) {
        size_t qrow = (size_t)(qw + s * 16 + l16) * E_;
#pragma unroll
        for (int nt = 0; nt < 8; nt++) {
            bf16x4 pk;
#pragma unroll
            for (int r = 0; r < 4; r++) pk[r] = (bf16)acc[s][nt][r];
            *(bf16x4*)&Ob[qrow + nh * 128 + nt * 16 + quad * 4] = pk;
        }
    }
}

// ---------------------------------------------------------------------------
// Kernel 5: sum the 2 k-split bf16 partials -> fp32 out[B,L,E]
// ---------------------------------------------------------------------------
__global__ void reduce_kernel(const bf16* __restrict__ Op, float* __restrict__ out) {
    size_t i = ((size_t)blockIdx.x * 256 + threadIdx.x) * 8;
    const size_t BLE = (size_t)B_ * L_ * E_;
    bf16x8 v0 = *(const bf16x8*)&Op[i];
    bf16x8 v1 = *(const bf16x8*)&Op[BLE + i];
    f32x4 o0, o1;
#pragma unroll
    for (int j = 0; j < 4; j++) o0[j] = (float)v0[j] + (float)v1[j];
#pragma unroll
    for (int j = 0; j < 4; j++) o1[j] = (float)v0[4 + j] + (float)v1[4 + j];
    *(f32x4*)&out[i] = o0;
    *(f32x4*)&out[i + 4] = o1;
}

// ---------------------------------------------------------------------------
extern "C" void kernel_launch(void* const* d_in, const int* in_sizes, int n_in,
                              void* d_out, int out_size, void* d_ws, size_t ws_size,
                              hipStream_t stream) {
    const float* x   = (const float*)d_in[0];
    const float* ipw = (const float*)d_in[1];
    const float* ipb = (const float*)d_in[2];
    const float* wg  = (const float*)d_in[3];
    const float* bg  = (const float*)d_in[4];

    char* ws = (char*)d_ws;
    // ws layout (bytes), total ~42.6 MB:
    //   Qs    [B,L,E]   bf16 @ 0          (8,388,608)
    //   Ks    [B,L,E]   bf16 @ 8388608    (8,388,608)
    //   XWT   [B,E,L]   bf16 @ 16777216   (8,388,608)
    //   o     [B,H,L]   f32  @ 25165824   (  262,144)
    //   Opart [2,B,L,E] bf16 @ 25427968   (16,777,216)
    //   Wcat  [768,256] bf16 @ 42205184   (  393,216)
    bf16*  Qs    = (bf16*)(ws);
    bf16*  Ks    = (bf16*)(ws + 8388608);
    bf16*  XWT   = (bf16*)(ws + 16777216);
    float* o     = (float*)(ws + 25165824);
    bf16*  Opart = (bf16*)(ws + 25427968);
    bf16*  Wcat  = (bf16*)(ws + 42205184);

    prep_weights<<<768, 256, 0, stream>>>(ipw, wg, Wcat);
    proj_kernel<<<dim3(256, 3), 256, 0, stream>>>(x, Wcat, ipb, bg, Qs, Ks, XWT);
    stats_kernel<<<dim3(16, 4, 8), 256, 0, stream>>>(Qs, Ks, o);
    pass2_kernel<<<dim3(16, 2, 8), 512, 0, stream>>>(Qs, Ks, XWT, o, Opart);
    reduce_kernel<<<2048, 256, 0, stream>>>(Opart, (float*)d_out);
}